// Round 7
// baseline (305.644 us; speedup 1.0000x reference)
//
#include <hip/hip_runtime.h>

typedef unsigned short u16;
typedef __bf16 bf16x8 __attribute__((ext_vector_type(8)));
typedef float f32x4 __attribute__((ext_vector_type(4)));
typedef unsigned u32x4 __attribute__((ext_vector_type(4)));  // native vec for nt-store

#define LOG2E 1.44269504088896f

__device__ inline u16 f2b(float f) {
    unsigned u = __float_as_uint(f);
    u += 0x7fff + ((u >> 16) & 1);
    return (u16)(u >> 16);
}
__device__ inline float b2f(u16 u) { return __uint_as_float(((unsigned)u) << 16); }
__device__ inline unsigned pk2(float a, float b) {
    return (unsigned)f2b(a) | ((unsigned)f2b(b) << 16);
}
__device__ inline uint4 pack8(float4 a, float4 b) {
    return uint4{pk2(a.x, a.y), pk2(a.z, a.w), pk2(b.x, b.y), pk2(b.z, b.w)};
}
__device__ inline f32x4 mfma_bf16(uint4 a, uint4 b, f32x4 c) {
    return __builtin_amdgcn_mfma_f32_16x16x32_bf16(
        __builtin_bit_cast(bf16x8, a), __builtin_bit_cast(bf16x8, b), c, 0, 0, 0);
}
// async global->LDS, 16 B per lane; LDS dest = wave-uniform base + lane*16
__device__ inline void ld16(const u16* g, u16* l) {
    __builtin_amdgcn_global_load_lds(
        (const __attribute__((address_space(1))) unsigned int*)g,
        (__attribute__((address_space(3))) unsigned int*)l, 16, 0, 0);
}
// 16-B nontemporal store (native ext-vector type required by the builtin)
__device__ inline void nt_store16(const void* src, void* dst) {
    __builtin_nontemporal_store(*(const u32x4*)src, (u32x4*)dst);
}
// P = exp2(k*LOG2E - c) applied to a bf16x8 fragment (nc = -c), repacked bf16.
__device__ inline uint4 expfrag(uint4 v, float nc) {
    float e[8];
#pragma unroll
    for (int i = 0; i < 4; ++i) {
        unsigned u = ((const unsigned*)&v)[i];
        e[2 * i] = exp2f(fmaf(b2f((u16)(u & 0xffff)), LOG2E, nc));
        e[2 * i + 1] = exp2f(fmaf(b2f((u16)(u >> 16)), LOG2E, nc));
    }
    uint4 r;
    asm("v_cvt_pk_bf16_f32 %0, %1, %2" : "=v"(r.x) : "v"(e[0]), "v"(e[1]));
    asm("v_cvt_pk_bf16_f32 %0, %1, %2" : "=v"(r.y) : "v"(e[2]), "v"(e[3]));
    asm("v_cvt_pk_bf16_f32 %0, %1, %2" : "=v"(r.z) : "v"(e[4]), "v"(e[5]));
    asm("v_cvt_pk_bf16_f32 %0, %1, %2" : "=v"(r.w) : "v"(e[6]), "v"(e[7]));
    return r;
}

// Tiled intermediate layout: KT/VT [b][nt(256)][d(256)][n-in-tile(32)] bf16.

// ---------------------------------------------------------------------------
// Weight prep (f32 -> bf16), plain layouts:
//   WkT[e][d] = Wqk[1][d][e],  WvT[e][d] = Wv[d][e],  Wqb[c][d] = Wqk[0][c][d]
// ---------------------------------------------------------------------------
__global__ __launch_bounds__(256) void prep_w(const float* __restrict__ Wqk,
                                              const float* __restrict__ Wv,
                                              u16* __restrict__ WkT,
                                              u16* __restrict__ WvT,
                                              u16* __restrict__ Wqb) {
    int idx = blockIdx.x * 256 + threadIdx.x;   // 0 .. 196607
    int which = idx >> 16;
    int i = (idx >> 8) & 255;
    int j = idx & 255;
    if (which == 0)
        WkT[i * 256 + j] = f2b(Wqk[65536 + j * 256 + i]);
    else if (which == 1)
        WvT[i * 256 + j] = f2b(Wv[j * 256 + i]);
    else
        Wqb[i * 256 + j] = f2b(Wqk[i * 256 + j]);
}

// ---------------------------------------------------------------------------
// Fused K+V projection (dbuf + swizzle + 4x4/wave tiling), TILED epilogue
// stores (NONTEMPORAL) + fused per-block online-softmax partials for K.
// ---------------------------------------------------------------------------
__global__ __launch_bounds__(256, 2) void gemm_kv(const float* __restrict__ A,
                                                  const u16* __restrict__ BtK,
                                                  const u16* __restrict__ BtV,
                                                  const float* __restrict__ biasK,
                                                  const float* __restrict__ biasV,
                                                  u16* __restrict__ KT,
                                                  u16* __restrict__ VT,
                                                  float* __restrict__ partial) {
    __shared__ __align__(16) u16 lds[36864];

    const int t = threadIdx.x;
    const int r0 = blockIdx.x * 64;
    const int w = t >> 6, lane = t & 63, l15 = lane & 15, q = lane >> 4;
    const int sq = ((lane & 3) ^ ((lane >> 3) & 3)) * 8;  // staging src swizzle
    const int qs = (q ^ ((l15 >> 1) & 3)) * 8;            // frag read swizzle
    const int awoff = (t >> 2) * 32 + sq;                 // swizzled A ds_write
    const int brr = t >> 2;

    f32x4 accK[4][4], accV[4][4];
#pragma unroll
    for (int rt = 0; rt < 4; ++rt)
#pragma unroll
        for (int ct = 0; ct < 4; ++ct) {
            accK[rt][ct] = f32x4{0.f, 0.f, 0.f, 0.f};
            accV[rt][ct] = f32x4{0.f, 0.f, 0.f, 0.f};
        }

    const float* Arow = A + (long)(r0 + brr) * 256 + (t & 3) * 8;
    float4 p0 = ((const float4*)Arow)[0], p1 = ((const float4*)Arow)[1];
    float4 c0_ = *(const float4*)(Arow + 32), c1_ = *(const float4*)(Arow + 36);
    float4 d0_ = *(const float4*)(Arow + 64), d1_ = *(const float4*)(Arow + 68);

    // prologue: stage k0=0 into buffer 0
    {
        u16* dK = lds + 4096 + w * 512;
#pragma unroll
        for (int j = 0; j < 4; ++j) {
            int br = j * 64 + brr;
            ld16(BtK + br * 256 + sq, dK + j * 2048);
            ld16(BtV + br * 256 + sq, dK + 8192 + j * 2048);
        }
    }
    *(uint4*)(lds + awoff) = pack8(p0, p1);
    __syncthreads();

#pragma unroll
    for (int t8 = 0; t8 < 8; ++t8) {
        const int cur = t8 & 1;
        if (t8 < 7) {  // stage next k-slab into the other buffer (async)
            const int k0 = (t8 + 1) * 32;
            u16* dK = lds + 4096 + (cur ^ 1) * 16384 + w * 512;
#pragma unroll
            for (int j = 0; j < 4; ++j) {
                int br = j * 64 + brr;
                ld16(BtK + br * 256 + k0 + sq, dK + j * 2048);
                ld16(BtV + br * 256 + k0 + sq, dK + 8192 + j * 2048);
            }
            *(uint4*)(lds + (cur ^ 1) * 2048 + awoff) = pack8(c0_, c1_);
            c0_ = d0_; c1_ = d1_;
            if (t8 < 5) {
                d0_ = *(const float4*)(Arow + (t8 + 3) * 32);
                d1_ = *(const float4*)(Arow + (t8 + 3) * 32 + 4);
            }
        }
        const u16* Asc = lds + cur * 2048;
        const u16* Bc = lds + 4096 + cur * 16384;
        uint4 af[4];
#pragma unroll
        for (int rt = 0; rt < 4; ++rt)
            af[rt] = *(const uint4*)(Asc + (rt * 16 + l15) * 32 + qs);
#pragma unroll
        for (int ct = 0; ct < 4; ++ct) {
            const int bo = (w * 64 + ct * 16 + l15) * 32 + qs;
            uint4 bK = *(const uint4*)(Bc + bo);
            uint4 bV = *(const uint4*)(Bc + 8192 + bo);
#pragma unroll
            for (int rt = 0; rt < 4; ++rt) {
                accK[rt][ct] = mfma_bf16(af[rt], bK, accK[rt][ct]);
                accV[rt][ct] = mfma_bf16(af[rt], bV, accV[rt][ct]);
            }
        }
        __syncthreads();
    }

    // epilogue: bias + LDS transpose + TILED nontemporal stores; pass 0 also
    // emits per-(b,d) online-softmax partials (m,s) over this block's 64 n.
    const int bb = r0 >> 13;
    const int nt0 = (r0 & 8191) >> 5;      // first of 2 tiles
    const int nch = nt0 >> 1;              // 0..127 partial slot
    u16* Ct = lds;
#pragma unroll
    for (int pass = 0; pass < 2; ++pass) {
        const f32x4(*acc)[4] = pass ? accV : accK;
        const float* bias = pass ? biasV : biasK;
        u16* CT = pass ? VT : KT;
#pragma unroll
        for (int ct = 0; ct < 4; ++ct) {
            const int col = w * 64 + ct * 16 + l15;
            const float bv = bias[col];
            ushort4 pks[4];
#pragma unroll
            for (int rt = 0; rt < 4; ++rt) {
                ushort4 pk;
                pk.x = f2b(acc[rt][ct][0] + bv);
                pk.y = f2b(acc[rt][ct][1] + bv);
                pk.z = f2b(acc[rt][ct][2] + bv);
                pk.w = f2b(acc[rt][ct][3] + bv);
                pks[rt] = pk;
                *(ushort4*)&Ct[col * 72 + rt * 16 + q * 4] = pk;
            }
            if (pass == 0) {
                float zm = -1e30f;
#pragma unroll
                for (int rt = 0; rt < 4; ++rt)
                    zm = fmaxf(zm,
                               fmaxf(fmaxf(b2f(pks[rt].x), b2f(pks[rt].y)),
                                     fmaxf(b2f(pks[rt].z), b2f(pks[rt].w))));
                zm = fmaxf(zm, __shfl_xor(zm, 16, 64));
                zm = fmaxf(zm, __shfl_xor(zm, 32, 64));
                zm *= LOG2E;   // z-space max
                float zs = 0.f;
#pragma unroll
                for (int rt = 0; rt < 4; ++rt) {
                    zs += exp2f(fmaf(b2f(pks[rt].x), LOG2E, -zm));
                    zs += exp2f(fmaf(b2f(pks[rt].y), LOG2E, -zm));
                    zs += exp2f(fmaf(b2f(pks[rt].z), LOG2E, -zm));
                    zs += exp2f(fmaf(b2f(pks[rt].w), LOG2E, -zm));
                }
                zs += __shfl_xor(zs, 16, 64);
                zs += __shfl_xor(zs, 32, 64);
                if (q == 0) {
                    float* pp =
                        partial + (((long)(bb * 128 + nch)) * 256 + col) * 2;
                    pp[0] = zm;
                    pp[1] = zs;
                }
            }
        }
        __syncthreads();
        {   // tiled nontemporal store
            const long tb = (((long)(bb * 256 + nt0)) * 256 + t) * 32;
#pragma unroll
            for (int j2 = 0; j2 < 2; ++j2)
#pragma unroll
                for (int g = 0; g < 4; ++g)
                    nt_store16(&Ct[t * 72 + j2 * 32 + g * 8],
                               CT + tb + j2 * 8192 + g * 8);
        }
        __syncthreads();
    }
}

// ---------------------------------------------------------------------------
// Combine per-chunk softmax partials, PARALLEL: grid (8 b, 8 dgrp), 256 thr.
// ---------------------------------------------------------------------------
__global__ __launch_bounds__(256) void stats2(const float* __restrict__ partial,
                                              float* __restrict__ ctab) {
    const int b = blockIdx.x, dg = blockIdx.y;
    const int t = threadIdx.x;
    const int d = dg * 32 + (t & 31);
    const int ci = t >> 5;
    float m = -1e30f, sum = 0.f;
#pragma unroll 4
    for (int k = 0; k < 16; ++k) {
        int i = ci * 16 + k;
        const float* pp = partial + (((long)(b * 128 + i)) * 256 + d) * 2;
        float mi = pp[0], si = pp[1];
        float M = fmaxf(m, mi);
        sum = sum * exp2f(m - M) + si * exp2f(mi - M);
        m = M;
    }
    __shared__ float red[512];
    red[t] = m;
    red[t + 256] = sum;
    __syncthreads();
    if (ci == 0) {
#pragma unroll
        for (int j = 1; j < 8; ++j) {
            float mi = red[t + j * 32], si = red[t + 256 + j * 32];
            float M = fmaxf(m, mi);
            sum = sum * exp2f(m - M) + si * exp2f(mi - M);
            m = M;
        }
        ctab[b * 256 + d] = m + log2f(sum);
    }
}

// ---------------------------------------------------------------------------
// Output GEMM: out[b][n][e] = sum_c X[n][c]*WfoldT[(b,e)][c]+outb.
// Nontemporal C stores.
// ---------------------------------------------------------------------------
__global__ __launch_bounds__(256, 3) void gemm_out(const float* __restrict__ A,
                                                   const u16* __restrict__ WfoldT,
                                                   const float* __restrict__ outb,
                                                   float* __restrict__ C) {
    __shared__ __align__(16) u16 lds[20480];
    const int t = threadIdx.x;
    const int r0 = blockIdx.x * 64;
    const int bb = r0 >> 13;
    const int w = t >> 6, lane = t & 63, l15 = lane & 15, q = lane >> 4;
    const int sq = ((lane & 3) ^ ((lane >> 3) & 3)) * 8;
    const int qs = (q ^ ((l15 >> 1) & 3)) * 8;
    const int awoff = (t >> 2) * 32 + sq;
    const int brr = t >> 2;
    const u16* Bt = WfoldT + (long)bb * 65536;

    f32x4 acc[4][4];
#pragma unroll
    for (int rt = 0; rt < 4; ++rt)
#pragma unroll
        for (int ct = 0; ct < 4; ++ct) acc[rt][ct] = f32x4{0.f, 0.f, 0.f, 0.f};

    const float* Arow = A + (long)(r0 + brr) * 256 + (t & 3) * 8;
    float4 p0 = ((const float4*)Arow)[0], p1 = ((const float4*)Arow)[1];
    float4 c0_ = *(const float4*)(Arow + 32), c1_ = *(const float4*)(Arow + 36);
    float4 d0_ = *(const float4*)(Arow + 64), d1_ = *(const float4*)(Arow + 68);

    {
        u16* dB = lds + 4096 + w * 512;
#pragma unroll
        for (int j = 0; j < 4; ++j)
            ld16(Bt + (j * 64 + brr) * 256 + sq, dB + j * 2048);
    }
    *(uint4*)(lds + awoff) = pack8(p0, p1);
    __syncthreads();

#pragma unroll
    for (int t8 = 0; t8 < 8; ++t8) {
        const int cur = t8 & 1;
        if (t8 < 7) {
            const int k0 = (t8 + 1) * 32;
            u16* dB = lds + 4096 + (cur ^ 1) * 8192 + w * 512;
#pragma unroll
            for (int j = 0; j < 4; ++j)
                ld16(Bt + (j * 64 + brr) * 256 + k0 + sq, dB + j * 2048);
            *(uint4*)(lds + (cur ^ 1) * 2048 + awoff) = pack8(c0_, c1_);
            c0_ = d0_; c1_ = d1_;
            if (t8 < 5) {
                d0_ = *(const float4*)(Arow + (t8 + 3) * 32);
                d1_ = *(const float4*)(Arow + (t8 + 3) * 32 + 4);
            }
        }
        const u16* Asc = lds + cur * 2048;
        const u16* Bc = lds + 4096 + cur * 8192;
        uint4 af[4];
#pragma unroll
        for (int rt = 0; rt < 4; ++rt)
            af[rt] = *(const uint4*)(Asc + (rt * 16 + l15) * 32 + qs);
#pragma unroll
        for (int ct = 0; ct < 4; ++ct) {
            uint4 bf = *(const uint4*)(Bc + (w * 64 + ct * 16 + l15) * 32 + qs);
#pragma unroll
            for (int rt = 0; rt < 4; ++rt)
                acc[rt][ct] = mfma_bf16(af[rt], bf, acc[rt][ct]);
        }
        __syncthreads();
    }

#pragma unroll
    for (int ct = 0; ct < 4; ++ct) {
        const int col = w * 64 + ct * 16 + l15;
        const float bv = outb[bb * 256 + col];
#pragma unroll
        for (int rt = 0; rt < 4; ++rt) {
            const long rbase = r0 + rt * 16 + q * 4;
#pragma unroll
            for (int r = 0; r < 4; ++r)
                __builtin_nontemporal_store(acc[rt][ct][r] + bv,
                                            &C[(rbase + r) * 256 + col]);
        }
    }
}

// ---------------------------------------------------------------------------
// lam GEMM: grid (64 = b x eh x dh, S) x 256 thr, block = 64 e x 128 d.
// Nontemporal lamP stores.
// ---------------------------------------------------------------------------
__global__ __launch_bounds__(256, 6) void gemm_lam(const u16* __restrict__ VT,
                                                   const u16* __restrict__ KT,
                                                   const float* __restrict__ ctab,
                                                   float* __restrict__ lamP,
                                                   int nk) {
    __shared__ __align__(16) u16 lds[12288];  // dbuf x (Vs 2048 | Ks 4096)
    const int t = threadIdx.x;
    const int bx = blockIdx.x;
    const int b = bx >> 3, e0 = ((bx >> 1) & 3) * 64, d0 = (bx & 1) * 128;
    const int s = blockIdx.y;
    const int w = t >> 6, lane = t & 63, l15 = lane & 15, q = lane >> 4;
    const int sq = ((lane & 3) ^ ((lane >> 3) & 3)) * 8;
    const int qs = (q ^ ((l15 >> 1) & 3)) * 8;

    const long nt0 = (long)s * nk;
    const u16* Vb = VT + ((long)b * 256 + nt0) * 8192;
    const u16* Kb = KT + ((long)b * 256 + nt0) * 8192;

    float nc0 = -ctab[b * 256 + d0 + w * 32 + l15];
    float nc1 = -ctab[b * 256 + d0 + w * 32 + 16 + l15];

    f32x4 acc[4][2];
#pragma unroll
    for (int rt = 0; rt < 4; ++rt) {
        acc[rt][0] = f32x4{0.f, 0.f, 0.f, 0.f};
        acc[rt][1] = f32x4{0.f, 0.f, 0.f, 0.f};
    }

    // prologue: stage tile 0 into buf 0
    ld16(Vb + (e0 + (t >> 2)) * 32 + sq, lds + w * 512);
    ld16(Kb + (d0 + (t >> 2)) * 32 + sq, lds + 2048 + w * 512);
    ld16(Kb + (d0 + 64 + (t >> 2)) * 32 + sq, lds + 4096 + w * 512);
    __syncthreads();

    for (int ks = 0; ks < nk; ++ks) {
        const int cur = ks & 1;
        if (ks + 1 < nk) {
            const u16* Vn = Vb + (long)(ks + 1) * 8192;
            const u16* Kn = Kb + (long)(ks + 1) * 8192;
            u16* dst = lds + (cur ^ 1) * 6144;
            ld16(Vn + (e0 + (t >> 2)) * 32 + sq, dst + w * 512);
            ld16(Kn + (d0 + (t >> 2)) * 32 + sq, dst + 2048 + w * 512);
            ld16(Kn + (d0 + 64 + (t >> 2)) * 32 + sq, dst + 4096 + w * 512);
        }
        const u16* Vs = lds + cur * 6144;
        const u16* Ks = Vs + 2048;
        uint4 bf0 = expfrag(*(const uint4*)(Ks + (w * 32 + l15) * 32 + qs), nc0);
        uint4 bf1 =
            expfrag(*(const uint4*)(Ks + (w * 32 + 16 + l15) * 32 + qs), nc1);
#pragma unroll
        for (int rt = 0; rt < 4; ++rt) {
            uint4 af = *(const uint4*)(Vs + (rt * 16 + l15) * 32 + qs);
            acc[rt][0] = mfma_bf16(af, bf0, acc[rt][0]);
            acc[rt][1] = mfma_bf16(af, bf1, acc[rt][1]);
        }
        __syncthreads();
    }

    // store partial lam[s]: rows (b, e0+..), cols d0+..  (nontemporal)
    float* outp = lamP + (long)s * 524288 + (long)b * 65536;
#pragma unroll
    for (int rt = 0; rt < 4; ++rt)
#pragma unroll
        for (int ct = 0; ct < 2; ++ct) {
            const int col = d0 + w * 32 + ct * 16 + l15;
            const int row = e0 + rt * 16 + q * 4;
#pragma unroll
            for (int r = 0; r < 4; ++r)
                __builtin_nontemporal_store(
                    acc[rt][ct][r], &outp[(long)(row + r) * 256 + col]);
        }
}

// ---------------------------------------------------------------------------
// lamT[i] = sum_s lamP[s][i]   (coalesced float4)
// ---------------------------------------------------------------------------
__global__ __launch_bounds__(256) void reduce_lam(const float* __restrict__ lamP,
                                                  float* __restrict__ lamT, int S) {
    int i = blockIdx.x * 256 + threadIdx.x;  // float4 index, 131072 total
    float4 v = ((const float4*)lamP)[i];
    for (int s = 1; s < S; ++s) {
        float4 p = ((const float4*)(lamP + (long)s * 524288))[i];
        v.x += p.x; v.y += p.y; v.z += p.z; v.w += p.w;
    }
    ((float4*)lamT)[i] = v;
}

// ---------------------------------------------------------------------------
// Fold GEMM: WfoldT[(b,e)][c] = sum_d bnT[(b,e)][d] * Wqb[c][d].
// ---------------------------------------------------------------------------
__global__ __launch_bounds__(256, 4) void gemm_fold(const u16* __restrict__ Abn,
                                                    const u16* __restrict__ Wqb,
                                                    u16* __restrict__ WfoldT) {
    __shared__ __align__(16) u16 lds[4096];  // As 64x32, Bs 64x32
    u16* As = lds;
    u16* Bs = lds + 2048;

    const int t = threadIdx.x;
    const int r0 = blockIdx.x * 64;
    const int c0 = blockIdx.y * 64;
    const int w = t >> 6, lane = t & 63, l15 = lane & 15, q = lane >> 4;

    f32x4 acc[4];
#pragma unroll
    for (int c = 0; c < 4; ++c) acc[c] = f32x4{0.f, 0.f, 0.f, 0.f};

    const int br = t >> 2;
    const int bk = (t & 3) * 8;

    for (int k0 = 0; k0 < 256; k0 += 32) {
        ld16(Abn + (long)(r0 + br) * 256 + k0 + bk, As + w * 512);
        ld16(Wqb + (long)(c0 + br) * 256 + k0 + bk, Bs + w * 512);
        __syncthreads();
        uint4 af = *(const uint4*)(As + (w * 16 + l15) * 32 + q * 8);
#pragma unroll
        for (int c = 0; c < 4; ++c) {
            uint4 bf = *(const uint4*)(Bs + (c * 16 + l15) * 32 + q * 8);
            acc[c] = mfma_bf16(af, bf, acc[c]);
        }
        __syncthreads();
    }

#pragma unroll
    for (int c = 0; c < 4; ++c) {
        int col = c0 + c * 16 + l15;
#pragma unroll
        for (int r = 0; r < 4; ++r) {
            int row = r0 + w * 16 + q * 4 + r;
            WfoldT[(long)row * 256 + col] = f2b(acc[c][r]);
        }
    }
}

// ---------------------------------------------------------------------------
// BatchNorm over lam^T[(b*256+e)][d]: stats per d over 2048 (b,e) values.
// ---------------------------------------------------------------------------
__global__ __launch_bounds__(256) void bn_kernel(const float* __restrict__ lamT,
                                                 const float* __restrict__ gamma,
                                                 const float* __restrict__ beta,
                                                 u16* __restrict__ bnT) {
    const int d = blockIdx.x;
    const int t = threadIdx.x;
    float vals[8];
    float s = 0.f, ss = 0.f;
#pragma unroll
    for (int i = 0; i < 8; ++i) {
        float v = lamT[(long)(i * 256 + t) * 256 + d];
        vals[i] = v;
        s += v;
        ss += v * v;
    }
#pragma unroll
    for (int sh = 32; sh > 0; sh >>= 1) {
        s += __shfl_xor(s, sh, 64);
        ss += __shfl_xor(ss, sh, 64);
    }
    __shared__ float red[8];
    int w = t >> 6;
    if ((t & 63) == 0) {
        red[w] = s;
        red[w + 4] = ss;
    }
    __syncthreads();
    s = red[0] + red[1] + red[2] + red[3];
    ss = red[4] + red[5] + red[6] + red[7];
    float mean = s * (1.f / 2048.f);
    float var = ss * (1.f / 2048.f) - mean * mean;
    float scale = gamma[d] * rsqrtf(var + 1e-5f);
    float shift = beta[d] - mean * scale;
#pragma unroll
    for (int i = 0; i < 8; ++i)
        bnT[(long)(i * 256 + t) * 256 + d] = f2b(vals[i] * scale + shift);
}

// ---------------------------------------------------------------------------
// outb[(b,e)] = sum_d bq[d] * bnT[(b,e)][d] — one wave per (b,e) row.
// grid 512 x 256 thr (4 waves/block, 2048 rows).
// ---------------------------------------------------------------------------
__global__ __launch_bounds__(256) void outb_kernel(const float* __restrict__ bq,
                                                   const u16* __restrict__ bnT,
                                                   float* __restrict__ outb) {
    const int t = threadIdx.x;
    const int wv = t >> 6, lane = t & 63;
    const int row = blockIdx.x * 4 + wv;   // 0..2047
    ushort4 v = *(const ushort4*)(bnT + (long)row * 256 + lane * 4);
    float4 g = *(const float4*)(bq + lane * 4);
    float s = b2f(v.x) * g.x + b2f(v.y) * g.y + b2f(v.z) * g.z + b2f(v.w) * g.w;
#pragma unroll
    for (int sh = 32; sh > 0; sh >>= 1) s += __shfl_xor(s, sh, 64);
    if (lane == 0) outb[row] = s;
}

// ---------------------------------------------------------------------------
extern "C" void kernel_launch(void* const* d_in, const int* in_sizes, int n_in,
                              void* d_out, int out_size, void* d_ws, size_t ws_size,
                              hipStream_t stream) {
    const float* feat = (const float*)d_in[0];   // (8,8192,256) f32
    const float* W_qk = (const float*)d_in[1];   // (2,256,256) f32
    const float* b_qk = (const float*)d_in[2];   // (2,256) f32
    const float* W_v = (const float*)d_in[3];    // (256,256) f32
    const float* b_v = (const float*)d_in[4];    // (256,) f32
    const float* gamma = (const float*)d_in[5];  // (256,) f32
    const float* beta = (const float*)d_in[6];   // (256,) f32
    float* out = (float*)d_out;                  // (8,8192,256) f32

    char* ws = (char*)d_ws;
    u16* KT = (u16*)(ws);                        // tiled raw K, 33,554,432 B
    u16* VT = (u16*)(ws + 33554432);             // tiled V,     33,554,432 B
    u16* WkT = (u16*)(ws + 67108864);            // 131072 B
    u16* WvT = (u16*)(ws + 67239936);            // 131072 B
    u16* Wqb = (u16*)(ws + 67371008);            // 131072 B
    float* partial = (float*)(ws + 67502080);    // 2,097,152 B (m,s per chunk)
    float* ctab = (float*)(ws + 69599232);       // 8,192 B
    const size_t base = 69607424;
    float* lamP = (float*)(ws + base);           // S * 2,097,152 B
    size_t avail = (ws_size > base) ? ws_size - base : 0;
    int S = (avail >= 8u * 2097152u) ? 8
          : (avail >= 4u * 2097152u) ? 4 : 2;
    // post-lam buffers alias the dead K region (only written after gemm_lam):
    float* lamT = (float*)ws;                    // 2,097,152 B
    u16* bnT = (u16*)(ws + 2097152);             // 1,048,576 B
    u16* WfoldT = (u16*)(ws + 3145728);          // 1,048,576 B
    float* outb = (float*)(ws + 4194304);        // 8,192 B

    // 1. weight prep
    prep_w<<<768, 256, 0, stream>>>(W_qk, W_v, WkT, WvT, Wqb);
    // 2. fused K/V projection -> tiled layout + softmax partials (nt stores)
    gemm_kv<<<1024, 256, 0, stream>>>(feat, WkT, WvT, b_qk + 256, b_v, KT, VT,
                                      partial);
    // 3. combine partials -> c[b][d]  (parallel)
    stats2<<<dim3(8, 8), 256, 0, stream>>>(partial, ctab);
    // 4. lam partials, full coverage (P computed on the fly) + reduce
    gemm_lam<<<dim3(64, S), 256, 0, stream>>>(VT, KT, ctab, lamP, 8192 / (S * 32));
    reduce_lam<<<512, 256, 0, stream>>>(lamP, lamT, S);
    // 5. BN -> bn^T bf16
    bn_kernel<<<256, 256, 0, stream>>>(lamT, gamma, beta, bnT);
    // 6. folded query bias (wave-parallel)
    outb_kernel<<<512, 256, 0, stream>>>(b_qk, bnT, outb);
    // 7. Wfold^T = bn^T @ Wq^T
    gemm_fold<<<dim3(32, 4), 256, 0, stream>>>(bnT, Wqb, WfoldT);
    // 8. out = X @ Wfold (+outb), nontemporal C stores
    gemm_out<<<1024, 256, 0, stream>>>(feat, WfoldT, outb, out);
}

// Round 8
// 235.142 us; speedup vs baseline: 1.2998x; 1.2998x over previous
//
#include <hip/hip_runtime.h>

typedef unsigned short u16;
typedef __bf16 bf16x8 __attribute__((ext_vector_type(8)));
typedef float f32x4 __attribute__((ext_vector_type(4)));

#define LOG2E 1.44269504088896f

__device__ inline u16 f2b(float f) {
    unsigned u = __float_as_uint(f);
    u += 0x7fff + ((u >> 16) & 1);
    return (u16)(u >> 16);
}
__device__ inline float b2f(u16 u) { return __uint_as_float(((unsigned)u) << 16); }
__device__ inline unsigned pk2(float a, float b) {
    return (unsigned)f2b(a) | ((unsigned)f2b(b) << 16);
}
__device__ inline uint4 pack8(float4 a, float4 b) {
    return uint4{pk2(a.x, a.y), pk2(a.z, a.w), pk2(b.x, b.y), pk2(b.z, b.w)};
}
__device__ inline f32x4 mfma_bf16(uint4 a, uint4 b, f32x4 c) {
    return __builtin_amdgcn_mfma_f32_16x16x32_bf16(
        __builtin_bit_cast(bf16x8, a), __builtin_bit_cast(bf16x8, b), c, 0, 0, 0);
}
// async global->LDS, 16 B per lane; LDS dest = wave-uniform base + lane*16
__device__ inline void ld16(const u16* g, u16* l) {
    __builtin_amdgcn_global_load_lds(
        (const __attribute__((address_space(1))) unsigned int*)g,
        (__attribute__((address_space(3))) unsigned int*)l, 16, 0, 0);
}
// P = exp2(k*LOG2E - c) applied to a bf16x8 fragment (nc = -c), repacked bf16.
__device__ inline uint4 expfrag(uint4 v, float nc) {
    float e[8];
#pragma unroll
    for (int i = 0; i < 4; ++i) {
        unsigned u = ((const unsigned*)&v)[i];
        e[2 * i] = exp2f(fmaf(b2f((u16)(u & 0xffff)), LOG2E, nc));
        e[2 * i + 1] = exp2f(fmaf(b2f((u16)(u >> 16)), LOG2E, nc));
    }
    uint4 r;
    asm("v_cvt_pk_bf16_f32 %0, %1, %2" : "=v"(r.x) : "v"(e[0]), "v"(e[1]));
    asm("v_cvt_pk_bf16_f32 %0, %1, %2" : "=v"(r.y) : "v"(e[2]), "v"(e[3]));
    asm("v_cvt_pk_bf16_f32 %0, %1, %2" : "=v"(r.z) : "v"(e[4]), "v"(e[5]));
    asm("v_cvt_pk_bf16_f32 %0, %1, %2" : "=v"(r.w) : "v"(e[6]), "v"(e[7]));
    return r;
}

// Tiled intermediate layout: KT/VT [b][nt(256)][d(256)][n-in-tile(32)] bf16.

// ---------------------------------------------------------------------------
// Weight prep (f32 -> bf16), plain layouts:
//   WkT[e][d] = Wqk[1][d][e],  WvT[e][d] = Wv[d][e],  Wqb[c][d] = Wqk[0][c][d]
// ---------------------------------------------------------------------------
__global__ __launch_bounds__(256) void prep_w(const float* __restrict__ Wqk,
                                              const float* __restrict__ Wv,
                                              u16* __restrict__ WkT,
                                              u16* __restrict__ WvT,
                                              u16* __restrict__ Wqb) {
    int idx = blockIdx.x * 256 + threadIdx.x;   // 0 .. 196607
    int which = idx >> 16;
    int i = (idx >> 8) & 255;
    int j = idx & 255;
    if (which == 0)
        WkT[i * 256 + j] = f2b(Wqk[65536 + j * 256 + i]);
    else if (which == 1)
        WvT[i * 256 + j] = f2b(Wv[j * 256 + i]);
    else
        Wqb[i * 256 + j] = f2b(Wqk[i * 256 + j]);
}

// ---------------------------------------------------------------------------
// Fused K+V projection (dbuf + swizzle + 4x4/wave tiling).  This round:
// XCD-aware block swizzle + LANE-INTERLEAVED tiled stores (each wave store
// instruction = 1 KB contiguous, 16 full cache lines; no partial-line spray)
// + fused per-block online-softmax partials for K.
// ---------------------------------------------------------------------------
__global__ __launch_bounds__(256, 2) void gemm_kv(const float* __restrict__ A,
                                                  const u16* __restrict__ BtK,
                                                  const u16* __restrict__ BtV,
                                                  const float* __restrict__ biasK,
                                                  const float* __restrict__ biasV,
                                                  u16* __restrict__ KT,
                                                  u16* __restrict__ VT,
                                                  float* __restrict__ partial) {
    __shared__ __align__(16) u16 lds[36864];

    const int t = threadIdx.x;
    const int bid = blockIdx.x;
    const int swz = (bid & 7) * 128 + (bid >> 3);  // XCD-contiguous (1024%8==0)
    const int r0 = swz * 64;
    const int w = t >> 6, lane = t & 63, l15 = lane & 15, q = lane >> 4;
    const int sq = ((lane & 3) ^ ((lane >> 3) & 3)) * 8;  // staging src swizzle
    const int qs = (q ^ ((l15 >> 1) & 3)) * 8;            // frag read swizzle
    const int awoff = (t >> 2) * 32 + sq;                 // swizzled A ds_write
    const int brr = t >> 2;

    f32x4 accK[4][4], accV[4][4];
#pragma unroll
    for (int rt = 0; rt < 4; ++rt)
#pragma unroll
        for (int ct = 0; ct < 4; ++ct) {
            accK[rt][ct] = f32x4{0.f, 0.f, 0.f, 0.f};
            accV[rt][ct] = f32x4{0.f, 0.f, 0.f, 0.f};
        }

    const float* Arow = A + (long)(r0 + brr) * 256 + (t & 3) * 8;
    float4 p0 = ((const float4*)Arow)[0], p1 = ((const float4*)Arow)[1];
    float4 c0_ = *(const float4*)(Arow + 32), c1_ = *(const float4*)(Arow + 36);
    float4 d0_ = *(const float4*)(Arow + 64), d1_ = *(const float4*)(Arow + 68);

    // prologue: stage k0=0 into buffer 0
    {
        u16* dK = lds + 4096 + w * 512;
#pragma unroll
        for (int j = 0; j < 4; ++j) {
            int br = j * 64 + brr;
            ld16(BtK + br * 256 + sq, dK + j * 2048);
            ld16(BtV + br * 256 + sq, dK + 8192 + j * 2048);
        }
    }
    *(uint4*)(lds + awoff) = pack8(p0, p1);
    __syncthreads();

#pragma unroll
    for (int t8 = 0; t8 < 8; ++t8) {
        const int cur = t8 & 1;
        if (t8 < 7) {  // stage next k-slab into the other buffer (async)
            const int k0 = (t8 + 1) * 32;
            u16* dK = lds + 4096 + (cur ^ 1) * 16384 + w * 512;
#pragma unroll
            for (int j = 0; j < 4; ++j) {
                int br = j * 64 + brr;
                ld16(BtK + br * 256 + k0 + sq, dK + j * 2048);
                ld16(BtV + br * 256 + k0 + sq, dK + 8192 + j * 2048);
            }
            *(uint4*)(lds + (cur ^ 1) * 2048 + awoff) = pack8(c0_, c1_);
            c0_ = d0_; c1_ = d1_;
            if (t8 < 5) {
                d0_ = *(const float4*)(Arow + (t8 + 3) * 32);
                d1_ = *(const float4*)(Arow + (t8 + 3) * 32 + 4);
            }
        }
        const u16* Asc = lds + cur * 2048;
        const u16* Bc = lds + 4096 + cur * 16384;
        uint4 af[4];
#pragma unroll
        for (int rt = 0; rt < 4; ++rt)
            af[rt] = *(const uint4*)(Asc + (rt * 16 + l15) * 32 + qs);
#pragma unroll
        for (int ct = 0; ct < 4; ++ct) {
            const int bo = (w * 64 + ct * 16 + l15) * 32 + qs;
            uint4 bK = *(const uint4*)(Bc + bo);
            uint4 bV = *(const uint4*)(Bc + 8192 + bo);
#pragma unroll
            for (int rt = 0; rt < 4; ++rt) {
                accK[rt][ct] = mfma_bf16(af[rt], bK, accK[rt][ct]);
                accV[rt][ct] = mfma_bf16(af[rt], bV, accV[rt][ct]);
            }
        }
        __syncthreads();
    }

    // epilogue: bias + LDS transpose + lane-interleaved tiled stores; pass 0
    // also emits per-(b,d) online-softmax partials (m,s) over 64 n.
    const int bb = r0 >> 13;
    const int nt0 = (r0 & 8191) >> 5;      // first of 2 tiles
    const int nch = nt0 >> 1;              // 0..127 partial slot
    u16* Ct = lds;
#pragma unroll
    for (int pass = 0; pass < 2; ++pass) {
        const f32x4(*acc)[4] = pass ? accV : accK;
        const float* bias = pass ? biasV : biasK;
        u16* CT = pass ? VT : KT;
#pragma unroll
        for (int ct = 0; ct < 4; ++ct) {
            const int col = w * 64 + ct * 16 + l15;
            const float bv = bias[col];
            ushort4 pks[4];
#pragma unroll
            for (int rt = 0; rt < 4; ++rt) {
                ushort4 pk;
                pk.x = f2b(acc[rt][ct][0] + bv);
                pk.y = f2b(acc[rt][ct][1] + bv);
                pk.z = f2b(acc[rt][ct][2] + bv);
                pk.w = f2b(acc[rt][ct][3] + bv);
                pks[rt] = pk;
                *(ushort4*)&Ct[col * 72 + rt * 16 + q * 4] = pk;
            }
            if (pass == 0) {
                float zm = -1e30f;
#pragma unroll
                for (int rt = 0; rt < 4; ++rt)
                    zm = fmaxf(zm,
                               fmaxf(fmaxf(b2f(pks[rt].x), b2f(pks[rt].y)),
                                     fmaxf(b2f(pks[rt].z), b2f(pks[rt].w))));
                zm = fmaxf(zm, __shfl_xor(zm, 16, 64));
                zm = fmaxf(zm, __shfl_xor(zm, 32, 64));
                zm *= LOG2E;   // z-space max
                float zs = 0.f;
#pragma unroll
                for (int rt = 0; rt < 4; ++rt) {
                    zs += exp2f(fmaf(b2f(pks[rt].x), LOG2E, -zm));
                    zs += exp2f(fmaf(b2f(pks[rt].y), LOG2E, -zm));
                    zs += exp2f(fmaf(b2f(pks[rt].z), LOG2E, -zm));
                    zs += exp2f(fmaf(b2f(pks[rt].w), LOG2E, -zm));
                }
                zs += __shfl_xor(zs, 16, 64);
                zs += __shfl_xor(zs, 32, 64);
                if (q == 0) {
                    float* pp =
                        partial + (((long)(bb * 128 + nch)) * 256 + col) * 2;
                    pp[0] = zm;
                    pp[1] = zs;
                }
            }
        }
        __syncthreads();
        {   // lane-interleaved store: granule gi = g*256+t; instruction = 1 KB
            const long tbase = ((long)(bb * 256 + nt0)) * 8192;
#pragma unroll
            for (int j2 = 0; j2 < 2; ++j2)
#pragma unroll
                for (int g = 0; g < 4; ++g) {
                    const int gi = g * 256 + t;
                    *(uint4*)(CT + tbase + j2 * 8192 + (long)gi * 8) =
                        *(const uint4*)&Ct[(gi >> 2) * 72 + j2 * 32 +
                                           (t & 3) * 8];
                }
        }
        __syncthreads();
    }
}

// ---------------------------------------------------------------------------
// Combine per-chunk softmax partials, PARALLEL: grid (8 b, 8 dgrp), 256 thr.
// ---------------------------------------------------------------------------
__global__ __launch_bounds__(256) void stats2(const float* __restrict__ partial,
                                              float* __restrict__ ctab) {
    const int b = blockIdx.x, dg = blockIdx.y;
    const int t = threadIdx.x;
    const int d = dg * 32 + (t & 31);
    const int ci = t >> 5;
    float m = -1e30f, sum = 0.f;
#pragma unroll 4
    for (int k = 0; k < 16; ++k) {
        int i = ci * 16 + k;
        const float* pp = partial + (((long)(b * 128 + i)) * 256 + d) * 2;
        float mi = pp[0], si = pp[1];
        float M = fmaxf(m, mi);
        sum = sum * exp2f(m - M) + si * exp2f(mi - M);
        m = M;
    }
    __shared__ float red[512];
    red[t] = m;
    red[t + 256] = sum;
    __syncthreads();
    if (ci == 0) {
#pragma unroll
        for (int j = 1; j < 8; ++j) {
            float mi = red[t + j * 32], si = red[t + 256 + j * 32];
            float M = fmaxf(m, mi);
            sum = sum * exp2f(m - M) + si * exp2f(mi - M);
            m = M;
        }
        ctab[b * 256 + d] = m + log2f(sum);
    }
}

// ---------------------------------------------------------------------------
// Output GEMM: out[b][n][e] = sum_c X[n][c]*WfoldT[(b,e)][c]+outb.
// XCD swizzle; plain stores (full-line per 16-lane group already).
// ---------------------------------------------------------------------------
__global__ __launch_bounds__(256, 3) void gemm_out(const float* __restrict__ A,
                                                   const u16* __restrict__ WfoldT,
                                                   const float* __restrict__ outb,
                                                   float* __restrict__ C) {
    __shared__ __align__(16) u16 lds[20480];
    const int t = threadIdx.x;
    const int bid = blockIdx.x;
    const int swz = (bid & 7) * 128 + (bid >> 3);
    const int r0 = swz * 64;
    const int bb = r0 >> 13;
    const int w = t >> 6, lane = t & 63, l15 = lane & 15, q = lane >> 4;
    const int sq = ((lane & 3) ^ ((lane >> 3) & 3)) * 8;
    const int qs = (q ^ ((l15 >> 1) & 3)) * 8;
    const int awoff = (t >> 2) * 32 + sq;
    const int brr = t >> 2;
    const u16* Bt = WfoldT + (long)bb * 65536;

    f32x4 acc[4][4];
#pragma unroll
    for (int rt = 0; rt < 4; ++rt)
#pragma unroll
        for (int ct = 0; ct < 4; ++ct) acc[rt][ct] = f32x4{0.f, 0.f, 0.f, 0.f};

    const float* Arow = A + (long)(r0 + brr) * 256 + (t & 3) * 8;
    float4 p0 = ((const float4*)Arow)[0], p1 = ((const float4*)Arow)[1];
    float4 c0_ = *(const float4*)(Arow + 32), c1_ = *(const float4*)(Arow + 36);
    float4 d0_ = *(const float4*)(Arow + 64), d1_ = *(const float4*)(Arow + 68);

    {
        u16* dB = lds + 4096 + w * 512;
#pragma unroll
        for (int j = 0; j < 4; ++j)
            ld16(Bt + (j * 64 + brr) * 256 + sq, dB + j * 2048);
    }
    *(uint4*)(lds + awoff) = pack8(p0, p1);
    __syncthreads();

#pragma unroll
    for (int t8 = 0; t8 < 8; ++t8) {
        const int cur = t8 & 1;
        if (t8 < 7) {
            const int k0 = (t8 + 1) * 32;
            u16* dB = lds + 4096 + (cur ^ 1) * 8192 + w * 512;
#pragma unroll
            for (int j = 0; j < 4; ++j)
                ld16(Bt + (j * 64 + brr) * 256 + k0 + sq, dB + j * 2048);
            *(uint4*)(lds + (cur ^ 1) * 2048 + awoff) = pack8(c0_, c1_);
            c0_ = d0_; c1_ = d1_;
            if (t8 < 5) {
                d0_ = *(const float4*)(Arow + (t8 + 3) * 32);
                d1_ = *(const float4*)(Arow + (t8 + 3) * 32 + 4);
            }
        }
        const u16* Asc = lds + cur * 2048;
        const u16* Bc = lds + 4096 + cur * 8192;
        uint4 af[4];
#pragma unroll
        for (int rt = 0; rt < 4; ++rt)
            af[rt] = *(const uint4*)(Asc + (rt * 16 + l15) * 32 + qs);
#pragma unroll
        for (int ct = 0; ct < 4; ++ct) {
            uint4 bf = *(const uint4*)(Bc + (w * 64 + ct * 16 + l15) * 32 + qs);
#pragma unroll
            for (int rt = 0; rt < 4; ++rt)
                acc[rt][ct] = mfma_bf16(af[rt], bf, acc[rt][ct]);
        }
        __syncthreads();
    }

#pragma unroll
    for (int ct = 0; ct < 4; ++ct) {
        const int col = w * 64 + ct * 16 + l15;
        const float bv = outb[bb * 256 + col];
#pragma unroll
        for (int rt = 0; rt < 4; ++rt) {
            const long rbase = r0 + rt * 16 + q * 4;
#pragma unroll
            for (int r = 0; r < 4; ++r)
                C[(rbase + r) * 256 + col] = acc[rt][ct][r] + bv;
        }
    }
}

// ---------------------------------------------------------------------------
// lam GEMM: grid (64 = b x eh x dh, S) x 256 thr, block = 64 e x 128 d.
// Plain stores (reverted).
// ---------------------------------------------------------------------------
__global__ __launch_bounds__(256, 6) void gemm_lam(const u16* __restrict__ VT,
                                                   const u16* __restrict__ KT,
                                                   const float* __restrict__ ctab,
                                                   float* __restrict__ lamP,
                                                   int nk) {
    __shared__ __align__(16) u16 lds[12288];  // dbuf x (Vs 2048 | Ks 4096)
    const int t = threadIdx.x;
    const int bx = blockIdx.x;
    const int b = bx >> 3, e0 = ((bx >> 1) & 3) * 64, d0 = (bx & 1) * 128;
    const int s = blockIdx.y;
    const int w = t >> 6, lane = t & 63, l15 = lane & 15, q = lane >> 4;
    const int sq = ((lane & 3) ^ ((lane >> 3) & 3)) * 8;
    const int qs = (q ^ ((l15 >> 1) & 3)) * 8;

    const long nt0 = (long)s * nk;
    const u16* Vb = VT + ((long)b * 256 + nt0) * 8192;
    const u16* Kb = KT + ((long)b * 256 + nt0) * 8192;

    float nc0 = -ctab[b * 256 + d0 + w * 32 + l15];
    float nc1 = -ctab[b * 256 + d0 + w * 32 + 16 + l15];

    f32x4 acc[4][2];
#pragma unroll
    for (int rt = 0; rt < 4; ++rt) {
        acc[rt][0] = f32x4{0.f, 0.f, 0.f, 0.f};
        acc[rt][1] = f32x4{0.f, 0.f, 0.f, 0.f};
    }

    // prologue: stage tile 0 into buf 0
    ld16(Vb + (e0 + (t >> 2)) * 32 + sq, lds + w * 512);
    ld16(Kb + (d0 + (t >> 2)) * 32 + sq, lds + 2048 + w * 512);
    ld16(Kb + (d0 + 64 + (t >> 2)) * 32 + sq, lds + 4096 + w * 512);
    __syncthreads();

    for (int ks = 0; ks < nk; ++ks) {
        const int cur = ks & 1;
        if (ks + 1 < nk) {
            const u16* Vn = Vb + (long)(ks + 1) * 8192;
            const u16* Kn = Kb + (long)(ks + 1) * 8192;
            u16* dst = lds + (cur ^ 1) * 6144;
            ld16(Vn + (e0 + (t >> 2)) * 32 + sq, dst + w * 512);
            ld16(Kn + (d0 + (t >> 2)) * 32 + sq, dst + 2048 + w * 512);
            ld16(Kn + (d0 + 64 + (t >> 2)) * 32 + sq, dst + 4096 + w * 512);
        }
        const u16* Vs = lds + cur * 6144;
        const u16* Ks = Vs + 2048;
        uint4 bf0 = expfrag(*(const uint4*)(Ks + (w * 32 + l15) * 32 + qs), nc0);
        uint4 bf1 =
            expfrag(*(const uint4*)(Ks + (w * 32 + 16 + l15) * 32 + qs), nc1);
#pragma unroll
        for (int rt = 0; rt < 4; ++rt) {
            uint4 af = *(const uint4*)(Vs + (rt * 16 + l15) * 32 + qs);
            acc[rt][0] = mfma_bf16(af, bf0, acc[rt][0]);
            acc[rt][1] = mfma_bf16(af, bf1, acc[rt][1]);
        }
        __syncthreads();
    }

    // store partial lam[s]: rows (b, e0+..), cols d0+..
    float* outp = lamP + (long)s * 524288 + (long)b * 65536;
#pragma unroll
    for (int rt = 0; rt < 4; ++rt)
#pragma unroll
        for (int ct = 0; ct < 2; ++ct) {
            const int col = d0 + w * 32 + ct * 16 + l15;
            const int row = e0 + rt * 16 + q * 4;
#pragma unroll
            for (int r = 0; r < 4; ++r)
                outp[(long)(row + r) * 256 + col] = acc[rt][ct][r];
        }
}

// ---------------------------------------------------------------------------
// lamT[i] = sum_s lamP[s][i]   (coalesced float4)
// ---------------------------------------------------------------------------
__global__ __launch_bounds__(256) void reduce_lam(const float* __restrict__ lamP,
                                                  float* __restrict__ lamT, int S) {
    int i = blockIdx.x * 256 + threadIdx.x;  // float4 index, 131072 total
    float4 v = ((const float4*)lamP)[i];
    for (int s = 1; s < S; ++s) {
        float4 p = ((const float4*)(lamP + (long)s * 524288))[i];
        v.x += p.x; v.y += p.y; v.z += p.z; v.w += p.w;
    }
    ((float4*)lamT)[i] = v;
}

// ---------------------------------------------------------------------------
// Fold GEMM: WfoldT[(b,e)][c] = sum_d bnT[(b,e)][d] * Wqb[c][d].
// ---------------------------------------------------------------------------
__global__ __launch_bounds__(256, 4) void gemm_fold(const u16* __restrict__ Abn,
                                                    const u16* __restrict__ Wqb,
                                                    u16* __restrict__ WfoldT) {
    __shared__ __align__(16) u16 lds[4096];  // As 64x32, Bs 64x32
    u16* As = lds;
    u16* Bs = lds + 2048;

    const int t = threadIdx.x;
    const int r0 = blockIdx.x * 64;
    const int c0 = blockIdx.y * 64;
    const int w = t >> 6, lane = t & 63, l15 = lane & 15, q = lane >> 4;

    f32x4 acc[4];
#pragma unroll
    for (int c = 0; c < 4; ++c) acc[c] = f32x4{0.f, 0.f, 0.f, 0.f};

    const int br = t >> 2;
    const int bk = (t & 3) * 8;

    for (int k0 = 0; k0 < 256; k0 += 32) {
        ld16(Abn + (long)(r0 + br) * 256 + k0 + bk, As + w * 512);
        ld16(Wqb + (long)(c0 + br) * 256 + k0 + bk, Bs + w * 512);
        __syncthreads();
        uint4 af = *(const uint4*)(As + (w * 16 + l15) * 32 + q * 8);
#pragma unroll
        for (int c = 0; c < 4; ++c) {
            uint4 bf = *(const uint4*)(Bs + (c * 16 + l15) * 32 + q * 8);
            acc[c] = mfma_bf16(af, bf, acc[c]);
        }
        __syncthreads();
    }

#pragma unroll
    for (int c = 0; c < 4; ++c) {
        int col = c0 + c * 16 + l15;
#pragma unroll
        for (int r = 0; r < 4; ++r) {
            int row = r0 + w * 16 + q * 4 + r;
            WfoldT[(long)row * 256 + col] = f2b(acc[c][r]);
        }
    }
}

// ---------------------------------------------------------------------------
// BatchNorm over lam^T[(b*256+e)][d]: stats per d over 2048 (b,e) values.
// ---------------------------------------------------------------------------
__global__ __launch_bounds__(256) void bn_kernel(const float* __restrict__ lamT,
                                                 const float* __restrict__ gamma,
                                                 const float* __restrict__ beta,
                                                 u16* __restrict__ bnT) {
    const int d = blockIdx.x;
    const int t = threadIdx.x;
    float vals[8];
    float s = 0.f, ss = 0.f;
#pragma unroll
    for (int i = 0; i < 8; ++i) {
        float v = lamT[(long)(i * 256 + t) * 256 + d];
        vals[i] = v;
        s += v;
        ss += v * v;
    }
#pragma unroll
    for (int sh = 32; sh > 0; sh >>= 1) {
        s += __shfl_xor(s, sh, 64);
        ss += __shfl_xor(ss, sh, 64);
    }
    __shared__ float red[8];
    int w = t >> 6;
    if ((t & 63) == 0) {
        red[w] = s;
        red[w + 4] = ss;
    }
    __syncthreads();
    s = red[0] + red[1] + red[2] + red[3];
    ss = red[4] + red[5] + red[6] + red[7];
    float mean = s * (1.f / 2048.f);
    float var = ss * (1.f / 2048.f) - mean * mean;
    float scale = gamma[d] * rsqrtf(var + 1e-5f);
    float shift = beta[d] - mean * scale;
#pragma unroll
    for (int i = 0; i < 8; ++i)
        bnT[(long)(i * 256 + t) * 256 + d] = f2b(vals[i] * scale + shift);
}

// ---------------------------------------------------------------------------
// outb[(b,e)] = sum_d bq[d] * bnT[(b,e)][d] — one wave per (b,e) row.
// ---------------------------------------------------------------------------
__global__ __launch_bounds__(256) void outb_kernel(const float* __restrict__ bq,
                                                   const u16* __restrict__ bnT,
                                                   float* __restrict__ outb) {
    const int t = threadIdx.x;
    const int wv = t >> 6, lane = t & 63;
    const int row = blockIdx.x * 4 + wv;   // 0..2047
    ushort4 v = *(const ushort4*)(bnT + (long)row * 256 + lane * 4);
    float4 g = *(const float4*)(bq + lane * 4);
    float s = b2f(v.x) * g.x + b2f(v.y) * g.y + b2f(v.z) * g.z + b2f(v.w) * g.w;
#pragma unroll
    for (int sh = 32; sh > 0; sh >>= 1) s += __shfl_xor(s, sh, 64);
    if (lane == 0) outb[row] = s;
}

// ---------------------------------------------------------------------------
extern "C" void kernel_launch(void* const* d_in, const int* in_sizes, int n_in,
                              void* d_out, int out_size, void* d_ws, size_t ws_size,
                              hipStream_t stream) {
    const float* feat = (const float*)d_in[0];   // (8,8192,256) f32
    const float* W_qk = (const float*)d_in[1];   // (2,256,256) f32
    const float* b_qk = (const float*)d_in[2];   // (2,256) f32
    const float* W_v = (const float*)d_in[3];    // (256,256) f32
    const float* b_v = (const float*)d_in[4];    // (256,) f32
    const float* gamma = (const float*)d_in[5];  // (256,) f32
    const float* beta = (const float*)d_in[6];   // (256,) f32
    float* out = (float*)d_out;                  // (8,8192,256) f32

    char* ws = (char*)d_ws;
    u16* KT = (u16*)(ws);                        // tiled raw K, 33,554,432 B
    u16* VT = (u16*)(ws + 33554432);             // tiled V,     33,554,432 B
    u16* WkT = (u16*)(ws + 67108864);            // 131072 B
    u16* WvT = (u16*)(ws + 67239936);            // 131072 B
    u16* Wqb = (u16*)(ws + 67371008);            // 131072 B
    float* partial = (float*)(ws + 67502080);    // 2,097,152 B (m,s per chunk)
    float* ctab = (float*)(ws + 69599232);       // 8,192 B
    const size_t base = 69607424;
    float* lamP = (float*)(ws + base);           // S * 2,097,152 B
    size_t avail = (ws_size > base) ? ws_size - base : 0;
    int S = (avail >= 8u * 2097152u) ? 8
          : (avail >= 4u * 2097152u) ? 4 : 2;
    // post-lam buffers alias the dead K region (only written after gemm_lam):
    float* lamT = (float*)ws;                    // 2,097,152 B
    u16* bnT = (u16*)(ws + 2097152);             // 1,048,576 B
    u16* WfoldT = (u16*)(ws + 3145728);          // 1,048,576 B
    float* outb = (float*)(ws + 4194304);        // 8,192 B

    // 1. weight prep
    prep_w<<<768, 256, 0, stream>>>(W_qk, W_v, WkT, WvT, Wqb);
    // 2. fused K/V projection -> tiled layout + softmax partials
    gemm_kv<<<1024, 256, 0, stream>>>(feat, WkT, WvT, b_qk + 256, b_v, KT, VT,
                                      partial);
    // 3. combine partials -> c[b][d]  (parallel)
    stats2<<<dim3(8, 8), 256, 0, stream>>>(partial, ctab);
    // 4. lam partials, full coverage (P computed on the fly) + reduce
    gemm_lam<<<dim3(64, S), 256, 0, stream>>>(VT, KT, ctab, lamP, 8192 / (S * 32));
    reduce_lam<<<512, 256, 0, stream>>>(lamP, lamT, S);
    // 5. BN -> bn^T bf16
    bn_kernel<<<256, 256, 0, stream>>>(lamT, gamma, beta, bnT);
    // 6. folded query bias (wave-parallel)
    outb_kernel<<<512, 256, 0, stream>>>(b_qk, bnT, outb);
    // 7. Wfold^T = bn^T @ Wq^T
    gemm_fold<<<dim3(32, 4), 256, 0, stream>>>(bnT, Wqb, WfoldT);
    // 8. out = X @ Wfold (+outb)
    gemm_out<<<1024, 256, 0, stream>>>(feat, WfoldT, outb, out);
}